// Round 1
// 690.694 us; speedup vs baseline: 1.0462x; 1.0462x over previous
//
#include <hip/hip_runtime.h>
#include <hip/hip_bf16.h>

#define N_NODES 100000
#define N_EDGES 3200000
#define DIM 64
#define OUT_COLS 256
#define BUCKET_SHIFT 8                                   // 256 nodes per bucket
#define NBUCK ((N_NODES + 255) / 256)                    // 391
#define TILE 4096                                        // edges per binning block
#define NTILEBLK ((N_EDGES + TILE - 1) / TILE)           // 782

__device__ __forceinline__ unsigned short f2bf(float f) {
    __hip_bfloat16 b = __float2bfloat16(f);
    unsigned short u;
    __builtin_memcpy(&u, &b, 2);
    return u;
}
__device__ __forceinline__ float bflo(unsigned int p) { return __uint_as_float(p << 16); }
__device__ __forceinline__ float bfhi(unsigned int p) { return __uint_as_float(p & 0xFFFF0000u); }

// ---------------------------------------------------------------------------
// init: h = x ; h_bf = bf16(x) ; out[:, 0:64] = x
// ---------------------------------------------------------------------------
__global__ void init_kernel(const float* __restrict__ x,
                            float* __restrict__ h,
                            unsigned short* __restrict__ h_bf,
                            float* __restrict__ out) {
    int i = blockIdx.x * blockDim.x + threadIdx.x;   // float4 index
    const int total = N_NODES * DIM / 4;
    if (i < total) {
        float4 v = ((const float4*)x)[i];
        ((float4*)h)[i] = v;
        int elem = i * 4;
        int node = elem >> 6;
        int c    = elem & 63;
        *(float4*)&out[node * OUT_COLS + c] = v;
        unsigned int lo = (unsigned int)f2bf(v.x) | ((unsigned int)f2bf(v.y) << 16);
        unsigned int hi = (unsigned int)f2bf(v.z) | ((unsigned int)f2bf(v.w) << 16);
        *(uint2*)&h_bf[elem] = make_uint2(lo, hi);
    }
}

// ---------------------------------------------------------------------------
// bucket_hist: per-bucket edge counts (LDS-binned, 1 global atomic per
// (block,bucket) instead of per edge)
// ---------------------------------------------------------------------------
__global__ __launch_bounds__(256) void bucket_hist_kernel(const int* __restrict__ dst,
                                                          int* __restrict__ bucket_count) {
    __shared__ int lc[NBUCK];
    for (int b = threadIdx.x; b < NBUCK; b += 256) lc[b] = 0;
    __syncthreads();
    const int base = blockIdx.x * TILE;
#pragma unroll
    for (int k = 0; k < TILE / 256; ++k) {
        int e = base + k * 256 + threadIdx.x;
        if (e < N_EDGES) atomicAdd(&lc[((unsigned)dst[e]) >> BUCKET_SHIFT], 1);
    }
    __syncthreads();
    for (int b = threadIdx.x; b < NBUCK; b += 256) {
        int c = lc[b];
        if (c) atomicAdd(&bucket_count[b], c);
    }
}

// ---------------------------------------------------------------------------
// bucket_scan: exclusive scan of 391 bucket counts -> base & cursor
// ---------------------------------------------------------------------------
__global__ __launch_bounds__(512) void bucket_scan_kernel(const int* __restrict__ bucket_count,
                                                          int* __restrict__ bucket_base,
                                                          int* __restrict__ bucket_cursor,
                                                          int* __restrict__ offsets) {
    __shared__ int s[512];
    const int t = threadIdx.x;
    int v = (t < NBUCK) ? bucket_count[t] : 0;
    s[t] = v;
    __syncthreads();
    for (int off = 1; off < 512; off <<= 1) {
        int u = (t >= off) ? s[t - off] : 0;
        __syncthreads();
        s[t] += u;
        __syncthreads();
    }
    if (t < NBUCK) { int b = s[t] - v; bucket_base[t] = b; bucket_cursor[t] = b; }
    if (t == 0) offsets[N_NODES] = N_EDGES;
}

// ---------------------------------------------------------------------------
// binA: stage edges bucket-contiguously. NEW: block-local counting sort in
// LDS so the global stores are run-contiguous (coalesced) instead of one
// random 8B line per lane. Record = {src | dstlocal<<24, a}.
//   phase 1: per-bucket counts (LDS atomics), keep (dst, rank) in registers
//   phase 2: 391-entry scan -> local slot base; one global atomic per bucket
//            reserves the run; lgbase[b] = runStart - localExcl[b]
//   phase 3: scatter records into LDS stage[] sorted by bucket (+ bucket id)
//   phase 4: thread i writes stage[i] -> temp[lgbase[sbuck[i]] + i]
//            (consecutive slots of a bucket -> consecutive global addrs)
// ---------------------------------------------------------------------------
__global__ __launch_bounds__(256) void binA_kernel(const int* __restrict__ src,
                                                   const int* __restrict__ dst,
                                                   const float* __restrict__ a,
                                                   int* __restrict__ bucket_cursor,
                                                   int2* __restrict__ temp) {
    __shared__ int lcount[NBUCK];          // per-bucket count (this block)
    __shared__ int lscan[512];             // inclusive scan (padded)
    __shared__ int lgbase[NBUCK];          // globalRunStart - localExcl
    __shared__ int2 stage[TILE];           // 32 KB block-local sorted records
    __shared__ unsigned short sbuck[TILE]; // 8 KB bucket id per slot

    const int t = threadIdx.x;
    const int base = blockIdx.x * TILE;

    for (int b = t; b < NBUCK; b += 256) lcount[b] = 0;
    __syncthreads();

    // phase 1: count + rank
    int dv[TILE / 256], rk[TILE / 256];
#pragma unroll
    for (int k = 0; k < TILE / 256; ++k) {
        int e = base + k * 256 + t;
        dv[k] = 0; rk[k] = 0;
        if (e < N_EDGES) {
            int d = dst[e];
            dv[k] = d;
            rk[k] = atomicAdd(&lcount[((unsigned)d) >> BUCKET_SHIFT], 1);
        }
    }
    __syncthreads();

    // phase 2a: inclusive scan of counts (Hillis-Steele over 512, 2 elems/thread)
    lscan[t]       = (t < NBUCK) ? lcount[t] : 0;
    lscan[t + 256] = (t + 256 < NBUCK) ? lcount[t + 256] : 0;
    __syncthreads();
    for (int off = 1; off < 512; off <<= 1) {
        int u0 = (t >= off) ? lscan[t - off] : 0;
        int u1 = ((t + 256) >= off) ? lscan[t + 256 - off] : 0;
        __syncthreads();
        lscan[t] += u0;
        lscan[t + 256] += u1;
        __syncthreads();
    }
    // phase 2b: reserve global runs
    for (int b = t; b < NBUCK; b += 256) {
        int c = lcount[b];
        int excl = lscan[b] - c;
        int g = 0;
        if (c) g = atomicAdd(&bucket_cursor[b], c);
        lgbase[b] = g - excl;
    }
    __syncthreads();

    // phase 3: scatter into LDS, sorted by bucket
#pragma unroll
    for (int k = 0; k < TILE / 256; ++k) {
        int e = base + k * 256 + t;
        if (e < N_EDGES) {
            int d = dv[k];
            int b = ((unsigned)d) >> BUCKET_SHIFT;
            int slot = (lscan[b] - lcount[b]) + rk[k];
            stage[slot] = make_int2(src[e] | ((d & 255) << 24), __float_as_int(a[e]));
            sbuck[slot] = (unsigned short)b;
        }
    }
    __syncthreads();

    // phase 4: coalesced run-contiguous writeout
    const int cntT = min(TILE, N_EDGES - base);
    for (int i = t; i < cntT; i += 256) {
        temp[lgbase[sbuck[i]] + i] = stage[i];
    }
}

// ---------------------------------------------------------------------------
// binB: one block per bucket. Per-node counts + scan in LDS (produces
// offsets), then scatter to exact CSR slots via LDS cursors. All random
// writes stay in a ~64 KB window -> XCD-local L2, no HBM line bouncing.
// ---------------------------------------------------------------------------
__global__ __launch_bounds__(256) void binB_kernel(const int2* __restrict__ temp,
                                                   const int* __restrict__ bucket_base,
                                                   const int* __restrict__ bucket_count,
                                                   int* __restrict__ offsets,
                                                   int2* __restrict__ edges) {
    const int b = blockIdx.x;
    const int node0 = b << BUCKET_SHIFT;
    const int nodes = min(256, N_NODES - node0);
    const int beg = bucket_base[b];
    const int cnt = bucket_count[b];
    const int t = threadIdx.x;

    __shared__ int ncount[256];
    __shared__ int ssc[256];
    __shared__ int ncur[256];
    ncount[t] = 0;
    __syncthreads();
    for (int i = t; i < cnt; i += 256) {
        unsigned w0 = (unsigned)temp[beg + i].x;
        atomicAdd(&ncount[w0 >> 24], 1);
    }
    __syncthreads();
    int v = ncount[t];
    ssc[t] = v;
    __syncthreads();
    for (int off = 1; off < 256; off <<= 1) {
        int u = (t >= off) ? ssc[t - off] : 0;
        __syncthreads();
        ssc[t] += u;
        __syncthreads();
    }
    int excl = ssc[t] - v;
    if (t < nodes) offsets[node0 + t] = beg + excl;
    ncur[t] = beg + excl;
    __syncthreads();
    for (int i = t; i < cnt; i += 256) {
        int2 r = temp[beg + i];
        int loc = ((unsigned)r.x) >> 24;
        int pos = atomicAdd(&ncur[loc], 1);
        edges[pos] = make_int2(r.x & 0xFFFFFF, r.y);
    }
}

// ---------------------------------------------------------------------------
// gather: hn[v][:] = sum over edges (u->v) of a_e * h_bf[u][:]
// Half-wave (32 lanes) per node; lane covers 2 feature cols via bf16x2 load.
// ---------------------------------------------------------------------------
__global__ __launch_bounds__(256) void gather_kernel(
        const unsigned short* __restrict__ h_bf,
        const int2* __restrict__ edges,
        const int* __restrict__ offsets,
        float* __restrict__ hn) {
    const int lane   = threadIdx.x & 63;
    const int half   = lane >> 5;
    const int sub    = lane & 31;
    const int waveid = (blockIdx.x * blockDim.x + threadIdx.x) >> 6;
    const int node   = waveid * 2 + half;
    if (node >= N_NODES) return;

    const int beg = offsets[node];
    const int end = offsets[node + 1];
    const int col2 = sub * 2;

    float al0 = 0.f, al1 = 0.f, al2 = 0.f, al3 = 0.f;
    float ah0 = 0.f, ah1 = 0.f, ah2 = 0.f, ah3 = 0.f;
    int i = beg;
    for (; i + 4 <= end; i += 4) {
        int2 e0 = edges[i + 0];
        int2 e1 = edges[i + 1];
        int2 e2 = edges[i + 2];
        int2 e3 = edges[i + 3];
        unsigned int p0 = *(const unsigned int*)&h_bf[(size_t)e0.x * DIM + col2];
        unsigned int p1 = *(const unsigned int*)&h_bf[(size_t)e1.x * DIM + col2];
        unsigned int p2 = *(const unsigned int*)&h_bf[(size_t)e2.x * DIM + col2];
        unsigned int p3 = *(const unsigned int*)&h_bf[(size_t)e3.x * DIM + col2];
        float w0 = __int_as_float(e0.y);
        float w1 = __int_as_float(e1.y);
        float w2 = __int_as_float(e2.y);
        float w3 = __int_as_float(e3.y);
        al0 = fmaf(w0, bflo(p0), al0);  ah0 = fmaf(w0, bfhi(p0), ah0);
        al1 = fmaf(w1, bflo(p1), al1);  ah1 = fmaf(w1, bfhi(p1), ah1);
        al2 = fmaf(w2, bflo(p2), al2);  ah2 = fmaf(w2, bfhi(p2), ah2);
        al3 = fmaf(w3, bflo(p3), al3);  ah3 = fmaf(w3, bfhi(p3), ah3);
    }
    for (; i < end; ++i) {
        int2 e = edges[i];
        unsigned int p = *(const unsigned int*)&h_bf[(size_t)e.x * DIM + col2];
        float w = __int_as_float(e.y);
        al0 = fmaf(w, bflo(p), al0);
        ah0 = fmaf(w, bfhi(p), ah0);
    }
    float lo = (al0 + al1) + (al2 + al3);
    float hi = (ah0 + ah1) + (ah2 + ah3);
    *(float2*)&hn[(size_t)node * DIM + col2] = make_float2(lo, hi);
}

// ---------------------------------------------------------------------------
// update: t1 = h + h_n ; t2 = h * h_n
//         h <- leaky(t1 @ W1 + b1) + leaky(t2 @ W2 + b2)
// ---------------------------------------------------------------------------
__global__ __launch_bounds__(256) void update_kernel(
        float* __restrict__ h,
        unsigned short* __restrict__ h_bf,
        const float* __restrict__ hn,
        const float* __restrict__ W1,
        const float* __restrict__ b1,
        const float* __restrict__ W2,
        const float* __restrict__ b2,
        float* __restrict__ out,
        int out_col_base) {
    __shared__ float s_t1[2][4][DIM];
    __shared__ float s_t2[2][4][DIM];

    const int col  = threadIdx.x & 63;
    const int slot = threadIdx.x >> 6;

    float w1c[DIM], w2c[DIM];
#pragma unroll
    for (int k = 0; k < DIM; ++k) {
        w1c[k] = W1[k * DIM + col];
        w2c[k] = W2[k * DIM + col];
    }
    const float bb1 = b1[col];
    const float bb2 = b2[col];

    int buf = 0;
    for (int base = blockIdx.x * 4; base < N_NODES; base += gridDim.x * 4, buf ^= 1) {
        const int node = base + slot;
        const bool valid = (node < N_NODES);
        float hv = 0.f, hnv = 0.f;
        if (valid) {
            hv  = h[node * DIM + col];
            hnv = hn[node * DIM + col];
        }
        s_t1[buf][slot][col] = hv + hnv;
        s_t2[buf][slot][col] = hv * hnv;
        __syncthreads();

        float acc1 = bb1, acc2 = bb2;
        const float4* t1v = (const float4*)s_t1[buf][slot];
        const float4* t2v = (const float4*)s_t2[buf][slot];
#pragma unroll
        for (int k0 = 0; k0 < DIM / 4; ++k0) {
            float4 t1 = t1v[k0];
            float4 t2 = t2v[k0];
            acc1 = fmaf(t1.x, w1c[4 * k0 + 0], acc1);
            acc1 = fmaf(t1.y, w1c[4 * k0 + 1], acc1);
            acc1 = fmaf(t1.z, w1c[4 * k0 + 2], acc1);
            acc1 = fmaf(t1.w, w1c[4 * k0 + 3], acc1);
            acc2 = fmaf(t2.x, w2c[4 * k0 + 0], acc2);
            acc2 = fmaf(t2.y, w2c[4 * k0 + 1], acc2);
            acc2 = fmaf(t2.z, w2c[4 * k0 + 2], acc2);
            acc2 = fmaf(t2.w, w2c[4 * k0 + 3], acc2);
        }

        if (valid) {
            float r1 = acc1 > 0.f ? acc1 : 0.01f * acc1;
            float r2 = acc2 > 0.f ? acc2 : 0.01f * acc2;
            float hnew = r1 + r2;
            h[node * DIM + col] = hnew;
            h_bf[node * DIM + col] = f2bf(hnew);
            out[node * OUT_COLS + out_col_base + col] = hnew;
        }
    }
}

// ---------------------------------------------------------------------------
extern "C" void kernel_launch(void* const* d_in, const int* in_sizes, int n_in,
                              void* d_out, int out_size, void* d_ws, size_t ws_size,
                              hipStream_t stream) {
    const float* x   = (const float*)d_in[0];
    const float* a   = (const float*)d_in[1];
    const float* W1s = (const float*)d_in[2];
    const float* b1s = (const float*)d_in[3];
    const float* W2s = (const float*)d_in[4];
    const float* b2s = (const float*)d_in[5];
    const int*   src = (const int*)d_in[6];
    const int*   dst = (const int*)d_in[7];
    float* out = (float*)d_out;

    // workspace layout
    float* h  = (float*)d_ws;                              // [N, 64] fp32
    float* hn = h + (size_t)N_NODES * DIM;                 // [N, 64] fp32 (doubles as binA staging: 3.2M int2 = 25.6 MB exactly)
    unsigned short* h_bf = (unsigned short*)(hn + (size_t)N_NODES * DIM); // [N,64] bf16
    int* offsets       = (int*)(h_bf + (size_t)N_NODES * DIM);  // [N+1]
    int* bucket_count  = offsets + N_NODES + 1;            // [NBUCK]
    int* bucket_base   = bucket_count + NBUCK;             // [NBUCK]
    int* bucket_cursor = bucket_base + NBUCK;              // [NBUCK]
    uintptr_t p = (uintptr_t)(bucket_cursor + NBUCK);
    p = (p + 15) & ~(uintptr_t)15;
    int2* edges = (int2*)p;                                // [E]
    int2* temp  = (int2*)hn;                               // binA staging

    // h = x ; h_bf = bf16(x) ; out[:, :64] = x
    {
        int total = N_NODES * DIM / 4;
        init_kernel<<<(total + 255) / 256, 256, 0, stream>>>(x, h, h_bf, out);
    }

    // CSR build: bucket-hist -> tiny scan -> bin (LDS-sorted, coalesced runs) -> place (L2-local)
    hipMemsetAsync(bucket_count, 0, NBUCK * sizeof(int), stream);
    bucket_hist_kernel<<<NTILEBLK, 256, 0, stream>>>(dst, bucket_count);
    bucket_scan_kernel<<<1, 512, 0, stream>>>(bucket_count, bucket_base, bucket_cursor, offsets);
    binA_kernel<<<NTILEBLK, 256, 0, stream>>>(src, dst, a, bucket_cursor, temp);
    binB_kernel<<<NBUCK, 256, 0, stream>>>(temp, bucket_base, bucket_count, offsets, edges);

    for (int l = 0; l < 3; ++l) {
        int waves = (N_NODES + 1) / 2;
        int blocks = (waves * 64 + 255) / 256;
        gather_kernel<<<blocks, 256, 0, stream>>>(h_bf, edges, offsets, hn);
        update_kernel<<<2048, 256, 0, stream>>>(
            h, h_bf, hn,
            W1s + (size_t)l * DIM * DIM, b1s + (size_t)l * DIM,
            W2s + (size_t)l * DIM * DIM, b2s + (size_t)l * DIM,
            out, (l + 1) * DIM);
    }
}

// Round 2
// 558.730 us; speedup vs baseline: 1.2933x; 1.2362x over previous
//
#include <hip/hip_runtime.h>
#include <hip/hip_bf16.h>

#define N_NODES 100000
#define N_EDGES 3200000
#define DIM 64
#define OUT_COLS 256
#define BUCKET_SHIFT 8                                   // 256 nodes per bucket
#define NBUCK ((N_NODES + 255) / 256)                    // 391
#define TILE 4096                                        // edges per binning block
#define NTILEBLK ((N_EDGES + TILE - 1) / TILE)           // 782
#define NODE_TILES ((N_NODES + 63) / 64)                 // 1563 (64 nodes / block)
#define WFRAG_PER_LAYER (2 * 2 * 4 * 64 * 8)             // 8192 bf16 per layer

typedef __attribute__((ext_vector_type(8))) short short8;
typedef __attribute__((ext_vector_type(4))) float f32x4;

__device__ __forceinline__ unsigned short f2bf(float f) {
    __hip_bfloat16 b = __float2bfloat16(f);
    unsigned short u;
    __builtin_memcpy(&u, &b, 2);
    return u;
}
__device__ __forceinline__ unsigned int pkbf(float a, float b) {
    return (unsigned int)f2bf(a) | ((unsigned int)f2bf(b) << 16);
}
__device__ __forceinline__ float bflo(unsigned int p) { return __uint_as_float(p << 16); }
__device__ __forceinline__ float bfhi(unsigned int p) { return __uint_as_float(p & 0xFFFF0000u); }

// ---------------------------------------------------------------------------
// init: h = x ; h_bf = bf16(x) ; out[:, 0:64] = x
// ---------------------------------------------------------------------------
__global__ void init_kernel(const float* __restrict__ x,
                            float* __restrict__ h,
                            unsigned short* __restrict__ h_bf,
                            float* __restrict__ out) {
    int i = blockIdx.x * blockDim.x + threadIdx.x;   // float4 index
    const int total = N_NODES * DIM / 4;
    if (i < total) {
        float4 v = ((const float4*)x)[i];
        ((float4*)h)[i] = v;
        int elem = i * 4;
        int node = elem >> 6;
        int c    = elem & 63;
        *(float4*)&out[node * OUT_COLS + c] = v;
        unsigned int lo = pkbf(v.x, v.y);
        unsigned int hi = pkbf(v.z, v.w);
        *(uint2*)&h_bf[elem] = make_uint2(lo, hi);
    }
}

// ---------------------------------------------------------------------------
// wprep: pack all 3 layers' W1/W2 into bf16 MFMA B-fragments.
// Layout: idx = ((((layer*2+mat)*2+kt)*4+ct)*64+lane)*8 + j
//   frag element (lane, j) = W[kt*32 + (lane>>4)*8 + j][ct*16 + (lane&15)]
// ---------------------------------------------------------------------------
__global__ __launch_bounds__(256) void wprep_kernel(const float* __restrict__ W1s,
                                                    const float* __restrict__ W2s,
                                                    unsigned short* __restrict__ wfrag) {
    int idx = blockIdx.x * 256 + threadIdx.x;
    if (idx >= 3 * WFRAG_PER_LAYER) return;
    int j     = idx & 7;
    int lane  = (idx >> 3) & 63;
    int ct    = (idx >> 9) & 3;
    int kt    = (idx >> 11) & 1;
    int mat   = (idx >> 12) & 1;
    int layer = idx >> 13;
    int k   = kt * 32 + (lane >> 4) * 8 + j;
    int col = ct * 16 + (lane & 15);
    const float* W = (mat ? W2s : W1s) + (size_t)layer * DIM * DIM;
    wfrag[idx] = f2bf(W[k * DIM + col]);
}

// ---------------------------------------------------------------------------
// bucket_hist: per-bucket edge counts
// ---------------------------------------------------------------------------
__global__ __launch_bounds__(256) void bucket_hist_kernel(const int* __restrict__ dst,
                                                          int* __restrict__ bucket_count) {
    __shared__ int lc[NBUCK];
    for (int b = threadIdx.x; b < NBUCK; b += 256) lc[b] = 0;
    __syncthreads();
    const int base = blockIdx.x * TILE;
#pragma unroll
    for (int k = 0; k < TILE / 256; ++k) {
        int e = base + k * 256 + threadIdx.x;
        if (e < N_EDGES) atomicAdd(&lc[((unsigned)dst[e]) >> BUCKET_SHIFT], 1);
    }
    __syncthreads();
    for (int b = threadIdx.x; b < NBUCK; b += 256) {
        int c = lc[b];
        if (c) atomicAdd(&bucket_count[b], c);
    }
}

// ---------------------------------------------------------------------------
// bucket_scan: exclusive scan of 391 bucket counts -> base & cursor
// ---------------------------------------------------------------------------
__global__ __launch_bounds__(512) void bucket_scan_kernel(const int* __restrict__ bucket_count,
                                                          int* __restrict__ bucket_base,
                                                          int* __restrict__ bucket_cursor,
                                                          int* __restrict__ offsets) {
    __shared__ int s[512];
    const int t = threadIdx.x;
    int v = (t < NBUCK) ? bucket_count[t] : 0;
    s[t] = v;
    __syncthreads();
    for (int off = 1; off < 512; off <<= 1) {
        int u = (t >= off) ? s[t - off] : 0;
        __syncthreads();
        s[t] += u;
        __syncthreads();
    }
    if (t < NBUCK) { int b = s[t] - v; bucket_base[t] = b; bucket_cursor[t] = b; }
    if (t == 0) offsets[N_NODES] = N_EDGES;
}

// ---------------------------------------------------------------------------
// binA: LDS counting-sort per block, coalesced run-contiguous writeout
// ---------------------------------------------------------------------------
__global__ __launch_bounds__(256) void binA_kernel(const int* __restrict__ src,
                                                   const int* __restrict__ dst,
                                                   const float* __restrict__ a,
                                                   int* __restrict__ bucket_cursor,
                                                   int2* __restrict__ temp) {
    __shared__ int lcount[NBUCK];
    __shared__ int lscan[512];
    __shared__ int lgbase[NBUCK];
    __shared__ int2 stage[TILE];
    __shared__ unsigned short sbuck[TILE];

    const int t = threadIdx.x;
    const int base = blockIdx.x * TILE;

    for (int b = t; b < NBUCK; b += 256) lcount[b] = 0;
    __syncthreads();

    int dv[TILE / 256], rk[TILE / 256];
#pragma unroll
    for (int k = 0; k < TILE / 256; ++k) {
        int e = base + k * 256 + t;
        dv[k] = 0; rk[k] = 0;
        if (e < N_EDGES) {
            int d = dst[e];
            dv[k] = d;
            rk[k] = atomicAdd(&lcount[((unsigned)d) >> BUCKET_SHIFT], 1);
        }
    }
    __syncthreads();

    lscan[t]       = (t < NBUCK) ? lcount[t] : 0;
    lscan[t + 256] = (t + 256 < NBUCK) ? lcount[t + 256] : 0;
    __syncthreads();
    for (int off = 1; off < 512; off <<= 1) {
        int u0 = (t >= off) ? lscan[t - off] : 0;
        int u1 = ((t + 256) >= off) ? lscan[t + 256 - off] : 0;
        __syncthreads();
        lscan[t] += u0;
        lscan[t + 256] += u1;
        __syncthreads();
    }
    for (int b = t; b < NBUCK; b += 256) {
        int c = lcount[b];
        int excl = lscan[b] - c;
        int g = 0;
        if (c) g = atomicAdd(&bucket_cursor[b], c);
        lgbase[b] = g - excl;
    }
    __syncthreads();

#pragma unroll
    for (int k = 0; k < TILE / 256; ++k) {
        int e = base + k * 256 + t;
        if (e < N_EDGES) {
            int d = dv[k];
            int b = ((unsigned)d) >> BUCKET_SHIFT;
            int slot = (lscan[b] - lcount[b]) + rk[k];
            stage[slot] = make_int2(src[e] | ((d & 255) << 24), __float_as_int(a[e]));
            sbuck[slot] = (unsigned short)b;
        }
    }
    __syncthreads();

    const int cntT = min(TILE, N_EDGES - base);
    for (int i = t; i < cntT; i += 256) {
        temp[lgbase[sbuck[i]] + i] = stage[i];
    }
}

// ---------------------------------------------------------------------------
// binB: one block per bucket -> CSR offsets + edge placement (L2-local)
// ---------------------------------------------------------------------------
__global__ __launch_bounds__(256) void binB_kernel(const int2* __restrict__ temp,
                                                   const int* __restrict__ bucket_base,
                                                   const int* __restrict__ bucket_count,
                                                   int* __restrict__ offsets,
                                                   int2* __restrict__ edges) {
    const int b = blockIdx.x;
    const int node0 = b << BUCKET_SHIFT;
    const int nodes = min(256, N_NODES - node0);
    const int beg = bucket_base[b];
    const int cnt = bucket_count[b];
    const int t = threadIdx.x;

    __shared__ int ncount[256];
    __shared__ int ssc[256];
    __shared__ int ncur[256];
    ncount[t] = 0;
    __syncthreads();
    for (int i = t; i < cnt; i += 256) {
        unsigned w0 = (unsigned)temp[beg + i].x;
        atomicAdd(&ncount[w0 >> 24], 1);
    }
    __syncthreads();
    int v = ncount[t];
    ssc[t] = v;
    __syncthreads();
    for (int off = 1; off < 256; off <<= 1) {
        int u = (t >= off) ? ssc[t - off] : 0;
        __syncthreads();
        ssc[t] += u;
        __syncthreads();
    }
    int excl = ssc[t] - v;
    if (t < nodes) offsets[node0 + t] = beg + excl;
    ncur[t] = beg + excl;
    __syncthreads();
    for (int i = t; i < cnt; i += 256) {
        int2 r = temp[beg + i];
        int loc = ((unsigned)r.x) >> 24;
        int pos = atomicAdd(&ncur[loc], 1);
        edges[pos] = make_int2(r.x & 0xFFFFFF, r.y);
    }
}

// ---------------------------------------------------------------------------
// gather: hn[v][:] = sum over edges (u->v) of a_e * h_bf[u][:]
// ---------------------------------------------------------------------------
__global__ __launch_bounds__(256) void gather_kernel(
        const unsigned short* __restrict__ h_bf,
        const int2* __restrict__ edges,
        const int* __restrict__ offsets,
        float* __restrict__ hn) {
    const int lane   = threadIdx.x & 63;
    const int half   = lane >> 5;
    const int sub    = lane & 31;
    const int waveid = (blockIdx.x * blockDim.x + threadIdx.x) >> 6;
    const int node   = waveid * 2 + half;
    if (node >= N_NODES) return;

    const int beg = offsets[node];
    const int end = offsets[node + 1];
    const int col2 = sub * 2;

    float al0 = 0.f, al1 = 0.f, al2 = 0.f, al3 = 0.f;
    float ah0 = 0.f, ah1 = 0.f, ah2 = 0.f, ah3 = 0.f;
    int i = beg;
    for (; i + 4 <= end; i += 4) {
        int2 e0 = edges[i + 0];
        int2 e1 = edges[i + 1];
        int2 e2 = edges[i + 2];
        int2 e3 = edges[i + 3];
        unsigned int p0 = *(const unsigned int*)&h_bf[(size_t)e0.x * DIM + col2];
        unsigned int p1 = *(const unsigned int*)&h_bf[(size_t)e1.x * DIM + col2];
        unsigned int p2 = *(const unsigned int*)&h_bf[(size_t)e2.x * DIM + col2];
        unsigned int p3 = *(const unsigned int*)&h_bf[(size_t)e3.x * DIM + col2];
        float w0 = __int_as_float(e0.y);
        float w1 = __int_as_float(e1.y);
        float w2 = __int_as_float(e2.y);
        float w3 = __int_as_float(e3.y);
        al0 = fmaf(w0, bflo(p0), al0);  ah0 = fmaf(w0, bfhi(p0), ah0);
        al1 = fmaf(w1, bflo(p1), al1);  ah1 = fmaf(w1, bfhi(p1), ah1);
        al2 = fmaf(w2, bflo(p2), al2);  ah2 = fmaf(w2, bfhi(p2), ah2);
        al3 = fmaf(w3, bflo(p3), al3);  ah3 = fmaf(w3, bfhi(p3), ah3);
    }
    for (; i < end; ++i) {
        int2 e = edges[i];
        unsigned int p = *(const unsigned int*)&h_bf[(size_t)e.x * DIM + col2];
        float w = __int_as_float(e.y);
        al0 = fmaf(w, bflo(p), al0);
        ah0 = fmaf(w, bfhi(p), ah0);
    }
    float lo = (al0 + al1) + (al2 + al3);
    float hi = (ah0 + ah1) + (ah2 + ah3);
    *(float2*)&hn[(size_t)node * DIM + col2] = make_float2(lo, hi);
}

// ---------------------------------------------------------------------------
// update (MFMA): t1 = h + h_n ; t2 = h * h_n (bf16)
//   h <- leaky(t1 @ W1 + b1) + leaky(t2 @ W2 + b2)  via mfma_f32_16x16x32_bf16
// Block = 256 thr = 4 waves; 64 nodes per block (wave w: 16 nodes).
// LDS: t1/t2 bf16 [64][64] with 16B-unit XOR swizzle (byte ^= (row&7)<<4).
// W fragments pre-packed by wprep; each wave holds all 16 B-frags in regs.
// ---------------------------------------------------------------------------
__global__ __launch_bounds__(256) void update_kernel(
        float* __restrict__ h,
        unsigned short* __restrict__ h_bf,
        const float* __restrict__ hn,
        const unsigned short* __restrict__ wfrag,   // this layer's fragments
        const float* __restrict__ b1,
        const float* __restrict__ b2,
        float* __restrict__ out,
        int out_col_base) {
    __shared__ unsigned short t1s[64 * 64];   // 8 KB, swizzled A-tile
    __shared__ unsigned short t2s[64 * 64];   // 8 KB

    const int t    = threadIdx.x;
    const int lane = t & 63;
    const int wid  = t >> 6;
    const int node0 = blockIdx.x * 64;

    // ---- load W fragments (L2-hot, coalesced b128) ----
    short8 w1f[2][4], w2f[2][4];
#pragma unroll
    for (int kt = 0; kt < 2; ++kt)
#pragma unroll
        for (int ct = 0; ct < 4; ++ct) {
            w1f[kt][ct] = *(const short8*)(wfrag + (((0 * 2 + kt) * 4 + ct) * 64 + lane) * 8);
            w2f[kt][ct] = *(const short8*)(wfrag + (((1 * 2 + kt) * 4 + ct) * 64 + lane) * 8);
        }
    float bb1[4], bb2[4];
#pragma unroll
    for (int ct = 0; ct < 4; ++ct) {
        bb1[ct] = b1[ct * 16 + (lane & 15)];
        bb2[ct] = b2[ct * 16 + (lane & 15)];
    }

    // ---- phase A: build bf16 t1/t2 tiles in LDS (coalesced global reads) ----
    {
        const int row = t >> 2;             // 0..63
        const int kc  = (t & 3) * 16;       // k chunk of 16
        const int node = node0 + row;
        float tv1[16], tv2[16];
        if (node < N_NODES) {
            const float4* hp  = (const float4*)&h [(size_t)node * DIM + kc];
            const float4* hnp = (const float4*)&hn[(size_t)node * DIM + kc];
#pragma unroll
            for (int i = 0; i < 4; ++i) {
                float4 a = hp[i];
                float4 b = hnp[i];
                tv1[i * 4 + 0] = a.x + b.x;  tv2[i * 4 + 0] = a.x * b.x;
                tv1[i * 4 + 1] = a.y + b.y;  tv2[i * 4 + 1] = a.y * b.y;
                tv1[i * 4 + 2] = a.z + b.z;  tv2[i * 4 + 2] = a.z * b.z;
                tv1[i * 4 + 3] = a.w + b.w;  tv2[i * 4 + 3] = a.w * b.w;
            }
        } else {
#pragma unroll
            for (int i = 0; i < 16; ++i) { tv1[i] = 0.f; tv2[i] = 0.f; }
        }
        const int sw = (row & 7) << 4;
        const int base = row * 128 + (t & 3) * 32;
        uint4 q;
        q.x = pkbf(tv1[0], tv1[1]);  q.y = pkbf(tv1[2], tv1[3]);
        q.z = pkbf(tv1[4], tv1[5]);  q.w = pkbf(tv1[6], tv1[7]);
        *(uint4*)((char*)t1s + ((base) ^ sw)) = q;
        q.x = pkbf(tv1[8], tv1[9]);  q.y = pkbf(tv1[10], tv1[11]);
        q.z = pkbf(tv1[12], tv1[13]); q.w = pkbf(tv1[14], tv1[15]);
        *(uint4*)((char*)t1s + ((base + 16) ^ sw)) = q;
        q.x = pkbf(tv2[0], tv2[1]);  q.y = pkbf(tv2[2], tv2[3]);
        q.z = pkbf(tv2[4], tv2[5]);  q.w = pkbf(tv2[6], tv2[7]);
        *(uint4*)((char*)t2s + ((base) ^ sw)) = q;
        q.x = pkbf(tv2[8], tv2[9]);  q.y = pkbf(tv2[10], tv2[11]);
        q.z = pkbf(tv2[12], tv2[13]); q.w = pkbf(tv2[14], tv2[15]);
        *(uint4*)((char*)t2s + ((base + 16) ^ sw)) = q;
    }
    __syncthreads();

    // ---- phase B: MFMA ----
    const int arow = wid * 16 + (lane & 15);
    const int asw  = (arow & 7) << 4;
    short8 a1[2], a2[2];
#pragma unroll
    for (int kt = 0; kt < 2; ++kt) {
        int ab = (arow * 128 + kt * 64 + ((lane >> 4) << 4)) ^ asw;
        a1[kt] = *(const short8*)((const char*)t1s + ab);
        a2[kt] = *(const short8*)((const char*)t2s + ab);
    }

    f32x4 acc1[4], acc2[4];
#pragma unroll
    for (int ct = 0; ct < 4; ++ct) {
        acc1[ct] = (f32x4){bb1[ct], bb1[ct], bb1[ct], bb1[ct]};
        acc2[ct] = (f32x4){bb2[ct], bb2[ct], bb2[ct], bb2[ct]};
    }
#pragma unroll
    for (int ct = 0; ct < 4; ++ct) {
        acc1[ct] = __builtin_amdgcn_mfma_f32_16x16x32_bf16(a1[0], w1f[0][ct], acc1[ct], 0, 0, 0);
        acc1[ct] = __builtin_amdgcn_mfma_f32_16x16x32_bf16(a1[1], w1f[1][ct], acc1[ct], 0, 0, 0);
        acc2[ct] = __builtin_amdgcn_mfma_f32_16x16x32_bf16(a2[0], w2f[0][ct], acc2[ct], 0, 0, 0);
        acc2[ct] = __builtin_amdgcn_mfma_f32_16x16x32_bf16(a2[1], w2f[1][ct], acc2[ct], 0, 0, 0);
    }

    // ---- phase C: epilogue (leaky + add), write h / h_bf / out ----
#pragma unroll
    for (int ct = 0; ct < 4; ++ct) {
        const int col = ct * 16 + (lane & 15);
#pragma unroll
        for (int r = 0; r < 4; ++r) {
            const int grow = node0 + wid * 16 + (lane >> 4) * 4 + r;
            if (grow < N_NODES) {
                float v1 = acc1[ct][r]; v1 = v1 > 0.f ? v1 : 0.01f * v1;
                float v2 = acc2[ct][r]; v2 = v2 > 0.f ? v2 : 0.01f * v2;
                float hnew = v1 + v2;
                h[(size_t)grow * DIM + col] = hnew;
                h_bf[(size_t)grow * DIM + col] = f2bf(hnew);
                out[(size_t)grow * OUT_COLS + out_col_base + col] = hnew;
            }
        }
    }
}

// ---------------------------------------------------------------------------
extern "C" void kernel_launch(void* const* d_in, const int* in_sizes, int n_in,
                              void* d_out, int out_size, void* d_ws, size_t ws_size,
                              hipStream_t stream) {
    const float* x   = (const float*)d_in[0];
    const float* a   = (const float*)d_in[1];
    const float* W1s = (const float*)d_in[2];
    const float* b1s = (const float*)d_in[3];
    const float* W2s = (const float*)d_in[4];
    const float* b2s = (const float*)d_in[5];
    const int*   src = (const int*)d_in[6];
    const int*   dst = (const int*)d_in[7];
    float* out = (float*)d_out;

    // workspace layout
    float* h  = (float*)d_ws;                              // [N, 64] fp32
    float* hn = h + (size_t)N_NODES * DIM;                 // [N, 64] fp32 (doubles as binA staging)
    unsigned short* h_bf = (unsigned short*)(hn + (size_t)N_NODES * DIM); // [N,64] bf16
    int* offsets       = (int*)(h_bf + (size_t)N_NODES * DIM);  // [N+1]
    int* bucket_count  = offsets + N_NODES + 1;            // [NBUCK]
    int* bucket_base   = bucket_count + NBUCK;             // [NBUCK]
    int* bucket_cursor = bucket_base + NBUCK;              // [NBUCK]
    uintptr_t p = (uintptr_t)(bucket_cursor + NBUCK);
    p = (p + 15) & ~(uintptr_t)15;
    int2* edges = (int2*)p;                                // [E]
    int2* temp  = (int2*)hn;                               // binA staging
    uintptr_t p2 = (uintptr_t)(edges + N_EDGES);
    p2 = (p2 + 15) & ~(uintptr_t)15;
    unsigned short* wfrag = (unsigned short*)p2;           // [3 * 8192] bf16 frags

    // h = x ; h_bf = bf16(x) ; out[:, :64] = x
    {
        int total = N_NODES * DIM / 4;
        init_kernel<<<(total + 255) / 256, 256, 0, stream>>>(x, h, h_bf, out);
    }

    // pack weight fragments (all 3 layers, one tiny launch)
    wprep_kernel<<<(3 * WFRAG_PER_LAYER + 255) / 256, 256, 0, stream>>>(W1s, W2s, wfrag);

    // CSR build
    hipMemsetAsync(bucket_count, 0, NBUCK * sizeof(int), stream);
    bucket_hist_kernel<<<NTILEBLK, 256, 0, stream>>>(dst, bucket_count);
    bucket_scan_kernel<<<1, 512, 0, stream>>>(bucket_count, bucket_base, bucket_cursor, offsets);
    binA_kernel<<<NTILEBLK, 256, 0, stream>>>(src, dst, a, bucket_cursor, temp);
    binB_kernel<<<NBUCK, 256, 0, stream>>>(temp, bucket_base, bucket_count, offsets, edges);

    for (int l = 0; l < 3; ++l) {
        int waves = (N_NODES + 1) / 2;
        int blocks = (waves * 64 + 255) / 256;
        gather_kernel<<<blocks, 256, 0, stream>>>(h_bf, edges, offsets, hn);
        update_kernel<<<NODE_TILES, 256, 0, stream>>>(
            h, h_bf, hn,
            wfrag + (size_t)l * WFRAG_PER_LAYER,
            b1s + (size_t)l * DIM,
            b2s + (size_t)l * DIM,
            out, (l + 1) * DIM);
    }
}

// Round 3
// 520.902 us; speedup vs baseline: 1.3872x; 1.0726x over previous
//
#include <hip/hip_runtime.h>
#include <hip/hip_bf16.h>

#define N_NODES 100000
#define N_EDGES 3200000
#define DIM 64
#define OUT_COLS 256
#define BUCKET_SHIFT 8                                   // 256 nodes per bucket
#define NBUCK ((N_NODES + 255) / 256)                    // 391
#define TILE 4096                                        // edges per binning block
#define NTILEBLK ((N_EDGES + TILE - 1) / TILE)           // 782
#define NODE_TILES ((N_NODES + 63) / 64)                 // 1563 (64 nodes / block)
#define WFRAG_PER_LAYER (2 * 2 * 4 * 64 * 8)             // 8192 bf16 per layer

typedef __attribute__((ext_vector_type(8))) short short8;
typedef __attribute__((ext_vector_type(4))) float f32x4;

__device__ __forceinline__ unsigned short f2bf(float f) {
    __hip_bfloat16 b = __float2bfloat16(f);
    unsigned short u;
    __builtin_memcpy(&u, &b, 2);
    return u;
}
__device__ __forceinline__ unsigned int pkbf(float a, float b) {
    return (unsigned int)f2bf(a) | ((unsigned int)f2bf(b) << 16);
}
__device__ __forceinline__ float bflo(unsigned int p) { return __uint_as_float(p << 16); }
__device__ __forceinline__ float bfhi(unsigned int p) { return __uint_as_float(p & 0xFFFF0000u); }

// ---------------------------------------------------------------------------
// init: h = x ; h_bf = bf16(x) ; out[:, 0:64] = x
// ---------------------------------------------------------------------------
__global__ void init_kernel(const float* __restrict__ x,
                            float* __restrict__ h,
                            unsigned short* __restrict__ h_bf,
                            float* __restrict__ out) {
    int i = blockIdx.x * blockDim.x + threadIdx.x;   // float4 index
    const int total = N_NODES * DIM / 4;
    if (i < total) {
        float4 v = ((const float4*)x)[i];
        ((float4*)h)[i] = v;
        int elem = i * 4;
        int node = elem >> 6;
        int c    = elem & 63;
        *(float4*)&out[node * OUT_COLS + c] = v;
        unsigned int lo = pkbf(v.x, v.y);
        unsigned int hi = pkbf(v.z, v.w);
        *(uint2*)&h_bf[elem] = make_uint2(lo, hi);
    }
}

// ---------------------------------------------------------------------------
// wprep: pack all 3 layers' W1/W2 into bf16 MFMA B-fragments.
// ---------------------------------------------------------------------------
__global__ __launch_bounds__(256) void wprep_kernel(const float* __restrict__ W1s,
                                                    const float* __restrict__ W2s,
                                                    unsigned short* __restrict__ wfrag) {
    int idx = blockIdx.x * 256 + threadIdx.x;
    if (idx >= 3 * WFRAG_PER_LAYER) return;
    int j     = idx & 7;
    int lane  = (idx >> 3) & 63;
    int ct    = (idx >> 9) & 3;
    int kt    = (idx >> 11) & 1;
    int mat   = (idx >> 12) & 1;
    int layer = idx >> 13;
    int k   = kt * 32 + (lane >> 4) * 8 + j;
    int col = ct * 16 + (lane & 15);
    const float* W = (mat ? W2s : W1s) + (size_t)layer * DIM * DIM;
    wfrag[idx] = f2bf(W[k * DIM + col]);
}

// ---------------------------------------------------------------------------
// count: per-block LDS histogram of dst buckets -> mat[blk][b]. NO global
// atomics (replaces bucket_hist's 306K contended device-scope RMWs).
// ---------------------------------------------------------------------------
__global__ __launch_bounds__(256) void count_kernel(const int* __restrict__ dst,
                                                    int* __restrict__ mat) {
    __shared__ int lc[NBUCK];
    for (int b = threadIdx.x; b < NBUCK; b += 256) lc[b] = 0;
    __syncthreads();
    const int base = blockIdx.x * TILE;
#pragma unroll
    for (int k = 0; k < TILE / 256; ++k) {
        int e = base + k * 256 + threadIdx.x;
        if (e < N_EDGES) atomicAdd(&lc[((unsigned)dst[e]) >> BUCKET_SHIFT], 1);
    }
    __syncthreads();
    int* row = mat + (size_t)blockIdx.x * NBUCK;
    for (int b = threadIdx.x; b < NBUCK; b += 256) row[b] = lc[b];
}

// ---------------------------------------------------------------------------
// scan2: per-bucket column-exclusive scan of mat over the 782 blocks
// (in-place), emitting bucket totals. One block per bucket.
// ---------------------------------------------------------------------------
__global__ __launch_bounds__(256) void scan2_kernel(int* __restrict__ mat,
                                                    int* __restrict__ bucket_count) {
    const int b = blockIdx.x;
    const int t = threadIdx.x;
    int cpre[4];
    int s = 0;
#pragma unroll
    for (int j = 0; j < 4; ++j) {
        int blk = t * 4 + j;
        cpre[j] = s;                                  // exclusive prefix within thread
        int v = (blk < NTILEBLK) ? mat[(size_t)blk * NBUCK + b] : 0;
        s += v;
    }
    __shared__ int ss[256];
    ss[t] = s;
    __syncthreads();
    for (int off = 1; off < 256; off <<= 1) {
        int u = (t >= off) ? ss[t - off] : 0;
        __syncthreads();
        ss[t] += u;
        __syncthreads();
    }
    int excl = ss[t] - s;
#pragma unroll
    for (int j = 0; j < 4; ++j) {
        int blk = t * 4 + j;
        if (blk < NTILEBLK) mat[(size_t)blk * NBUCK + b] = excl + cpre[j];
    }
    if (t == 255) bucket_count[b] = ss[255];
}

// ---------------------------------------------------------------------------
// bucket_scan: exclusive scan of 391 bucket counts -> bucket_base
// ---------------------------------------------------------------------------
__global__ __launch_bounds__(512) void bucket_scan_kernel(const int* __restrict__ bucket_count,
                                                          int* __restrict__ bucket_base,
                                                          int* __restrict__ offsets) {
    __shared__ int s[512];
    const int t = threadIdx.x;
    int v = (t < NBUCK) ? bucket_count[t] : 0;
    s[t] = v;
    __syncthreads();
    for (int off = 1; off < 512; off <<= 1) {
        int u = (t >= off) ? s[t - off] : 0;
        __syncthreads();
        s[t] += u;
        __syncthreads();
    }
    if (t < NBUCK) bucket_base[t] = s[t] - v;
    if (t == 0) offsets[N_NODES] = N_EDGES;
}

// ---------------------------------------------------------------------------
// binA: LDS counting-sort per block, coalesced run-contiguous writeout.
// Run bases are now PRECOMPUTED (bucket_base + mat column prefix) -> zero
// global atomics in the entire CSR build.
// ---------------------------------------------------------------------------
__global__ __launch_bounds__(256) void binA_kernel(const int* __restrict__ src,
                                                   const int* __restrict__ dst,
                                                   const float* __restrict__ a,
                                                   const int* __restrict__ bucket_base,
                                                   const int* __restrict__ mat,
                                                   int2* __restrict__ temp) {
    __shared__ int lcount[NBUCK];
    __shared__ int lscan[512];
    __shared__ int lgbase[NBUCK];
    __shared__ int2 stage[TILE];
    __shared__ unsigned short sbuck[TILE];

    const int t = threadIdx.x;
    const int base = blockIdx.x * TILE;

    for (int b = t; b < NBUCK; b += 256) lcount[b] = 0;
    __syncthreads();

    // phase 1: count + rank (LDS atomics only)
    int dv[TILE / 256], rk[TILE / 256];
#pragma unroll
    for (int k = 0; k < TILE / 256; ++k) {
        int e = base + k * 256 + t;
        dv[k] = 0; rk[k] = 0;
        if (e < N_EDGES) {
            int d = dst[e];
            dv[k] = d;
            rk[k] = atomicAdd(&lcount[((unsigned)d) >> BUCKET_SHIFT], 1);
        }
    }
    __syncthreads();

    // phase 2a: inclusive scan of counts
    lscan[t]       = (t < NBUCK) ? lcount[t] : 0;
    lscan[t + 256] = (t + 256 < NBUCK) ? lcount[t + 256] : 0;
    __syncthreads();
    for (int off = 1; off < 512; off <<= 1) {
        int u0 = (t >= off) ? lscan[t - off] : 0;
        int u1 = ((t + 256) >= off) ? lscan[t + 256 - off] : 0;
        __syncthreads();
        lscan[t] += u0;
        lscan[t + 256] += u1;
        __syncthreads();
    }
    // phase 2b: run bases from precomputed column prefix (no atomics)
    {
        const int* row = mat + (size_t)blockIdx.x * NBUCK;
        for (int b = t; b < NBUCK; b += 256) {
            int excl = lscan[b] - lcount[b];
            lgbase[b] = bucket_base[b] + row[b] - excl;
        }
    }
    __syncthreads();

    // phase 3: scatter into LDS, sorted by bucket
#pragma unroll
    for (int k = 0; k < TILE / 256; ++k) {
        int e = base + k * 256 + t;
        if (e < N_EDGES) {
            int d = dv[k];
            int b = ((unsigned)d) >> BUCKET_SHIFT;
            int slot = (lscan[b] - lcount[b]) + rk[k];
            stage[slot] = make_int2(src[e] | ((d & 255) << 24), __float_as_int(a[e]));
            sbuck[slot] = (unsigned short)b;
        }
    }
    __syncthreads();

    // phase 4: coalesced run-contiguous writeout
    const int cntT = min(TILE, N_EDGES - base);
    for (int i = t; i < cntT; i += 256) {
        temp[lgbase[sbuck[i]] + i] = stage[i];
    }
}

// ---------------------------------------------------------------------------
// binB: one block per bucket -> CSR offsets + edge placement (L2-local)
// ---------------------------------------------------------------------------
__global__ __launch_bounds__(256) void binB_kernel(const int2* __restrict__ temp,
                                                   const int* __restrict__ bucket_base,
                                                   const int* __restrict__ bucket_count,
                                                   int* __restrict__ offsets,
                                                   int2* __restrict__ edges) {
    const int b = blockIdx.x;
    const int node0 = b << BUCKET_SHIFT;
    const int nodes = min(256, N_NODES - node0);
    const int beg = bucket_base[b];
    const int cnt = bucket_count[b];
    const int t = threadIdx.x;

    __shared__ int ncount[256];
    __shared__ int ssc[256];
    __shared__ int ncur[256];
    ncount[t] = 0;
    __syncthreads();
    for (int i = t; i < cnt; i += 256) {
        unsigned w0 = (unsigned)temp[beg + i].x;
        atomicAdd(&ncount[w0 >> 24], 1);
    }
    __syncthreads();
    int v = ncount[t];
    ssc[t] = v;
    __syncthreads();
    for (int off = 1; off < 256; off <<= 1) {
        int u = (t >= off) ? ssc[t - off] : 0;
        __syncthreads();
        ssc[t] += u;
        __syncthreads();
    }
    int excl = ssc[t] - v;
    if (t < nodes) offsets[node0 + t] = beg + excl;
    ncur[t] = beg + excl;
    __syncthreads();
    for (int i = t; i < cnt; i += 256) {
        int2 r = temp[beg + i];
        int loc = ((unsigned)r.x) >> 24;
        int pos = atomicAdd(&ncur[loc], 1);
        edges[pos] = make_int2(r.x & 0xFFFFFF, r.y);
    }
}

// ---------------------------------------------------------------------------
// gather: hn[v][:] = sum over edges (u->v) of a_e * h_bf[u][:]
// ---------------------------------------------------------------------------
__global__ __launch_bounds__(256) void gather_kernel(
        const unsigned short* __restrict__ h_bf,
        const int2* __restrict__ edges,
        const int* __restrict__ offsets,
        float* __restrict__ hn) {
    const int lane   = threadIdx.x & 63;
    const int half   = lane >> 5;
    const int sub    = lane & 31;
    const int waveid = (blockIdx.x * blockDim.x + threadIdx.x) >> 6;
    const int node   = waveid * 2 + half;
    if (node >= N_NODES) return;

    const int beg = offsets[node];
    const int end = offsets[node + 1];
    const int col2 = sub * 2;

    float al0 = 0.f, al1 = 0.f, al2 = 0.f, al3 = 0.f;
    float ah0 = 0.f, ah1 = 0.f, ah2 = 0.f, ah3 = 0.f;
    int i = beg;
    for (; i + 4 <= end; i += 4) {
        int2 e0 = edges[i + 0];
        int2 e1 = edges[i + 1];
        int2 e2 = edges[i + 2];
        int2 e3 = edges[i + 3];
        unsigned int p0 = *(const unsigned int*)&h_bf[(size_t)e0.x * DIM + col2];
        unsigned int p1 = *(const unsigned int*)&h_bf[(size_t)e1.x * DIM + col2];
        unsigned int p2 = *(const unsigned int*)&h_bf[(size_t)e2.x * DIM + col2];
        unsigned int p3 = *(const unsigned int*)&h_bf[(size_t)e3.x * DIM + col2];
        float w0 = __int_as_float(e0.y);
        float w1 = __int_as_float(e1.y);
        float w2 = __int_as_float(e2.y);
        float w3 = __int_as_float(e3.y);
        al0 = fmaf(w0, bflo(p0), al0);  ah0 = fmaf(w0, bfhi(p0), ah0);
        al1 = fmaf(w1, bflo(p1), al1);  ah1 = fmaf(w1, bfhi(p1), ah1);
        al2 = fmaf(w2, bflo(p2), al2);  ah2 = fmaf(w2, bfhi(p2), ah2);
        al3 = fmaf(w3, bflo(p3), al3);  ah3 = fmaf(w3, bfhi(p3), ah3);
    }
    for (; i < end; ++i) {
        int2 e = edges[i];
        unsigned int p = *(const unsigned int*)&h_bf[(size_t)e.x * DIM + col2];
        float w = __int_as_float(e.y);
        al0 = fmaf(w, bflo(p), al0);
        ah0 = fmaf(w, bfhi(p), ah0);
    }
    float lo = (al0 + al1) + (al2 + al3);
    float hi = (ah0 + ah1) + (ah2 + ah3);
    *(float2*)&hn[(size_t)node * DIM + col2] = make_float2(lo, hi);
}

// ---------------------------------------------------------------------------
// update (MFMA): t1 = h + h_n ; t2 = h * h_n (bf16)
//   h <- leaky(t1 @ W1 + b1) + leaky(t2 @ W2 + b2)  via mfma_f32_16x16x32_bf16
// ---------------------------------------------------------------------------
__global__ __launch_bounds__(256) void update_kernel(
        float* __restrict__ h,
        unsigned short* __restrict__ h_bf,
        const float* __restrict__ hn,
        const unsigned short* __restrict__ wfrag,
        const float* __restrict__ b1,
        const float* __restrict__ b2,
        float* __restrict__ out,
        int out_col_base) {
    __shared__ unsigned short t1s[64 * 64];
    __shared__ unsigned short t2s[64 * 64];

    const int t    = threadIdx.x;
    const int lane = t & 63;
    const int wid  = t >> 6;
    const int node0 = blockIdx.x * 64;

    short8 w1f[2][4], w2f[2][4];
#pragma unroll
    for (int kt = 0; kt < 2; ++kt)
#pragma unroll
        for (int ct = 0; ct < 4; ++ct) {
            w1f[kt][ct] = *(const short8*)(wfrag + (((0 * 2 + kt) * 4 + ct) * 64 + lane) * 8);
            w2f[kt][ct] = *(const short8*)(wfrag + (((1 * 2 + kt) * 4 + ct) * 64 + lane) * 8);
        }
    float bb1[4], bb2[4];
#pragma unroll
    for (int ct = 0; ct < 4; ++ct) {
        bb1[ct] = b1[ct * 16 + (lane & 15)];
        bb2[ct] = b2[ct * 16 + (lane & 15)];
    }

    {
        const int row = t >> 2;
        const int kc  = (t & 3) * 16;
        const int node = node0 + row;
        float tv1[16], tv2[16];
        if (node < N_NODES) {
            const float4* hp  = (const float4*)&h [(size_t)node * DIM + kc];
            const float4* hnp = (const float4*)&hn[(size_t)node * DIM + kc];
#pragma unroll
            for (int i = 0; i < 4; ++i) {
                float4 a = hp[i];
                float4 b = hnp[i];
                tv1[i * 4 + 0] = a.x + b.x;  tv2[i * 4 + 0] = a.x * b.x;
                tv1[i * 4 + 1] = a.y + b.y;  tv2[i * 4 + 1] = a.y * b.y;
                tv1[i * 4 + 2] = a.z + b.z;  tv2[i * 4 + 2] = a.z * b.z;
                tv1[i * 4 + 3] = a.w + b.w;  tv2[i * 4 + 3] = a.w * b.w;
            }
        } else {
#pragma unroll
            for (int i = 0; i < 16; ++i) { tv1[i] = 0.f; tv2[i] = 0.f; }
        }
        const int sw = (row & 7) << 4;
        const int base = row * 128 + (t & 3) * 32;
        uint4 q;
        q.x = pkbf(tv1[0], tv1[1]);  q.y = pkbf(tv1[2], tv1[3]);
        q.z = pkbf(tv1[4], tv1[5]);  q.w = pkbf(tv1[6], tv1[7]);
        *(uint4*)((char*)t1s + ((base) ^ sw)) = q;
        q.x = pkbf(tv1[8], tv1[9]);  q.y = pkbf(tv1[10], tv1[11]);
        q.z = pkbf(tv1[12], tv1[13]); q.w = pkbf(tv1[14], tv1[15]);
        *(uint4*)((char*)t1s + ((base + 16) ^ sw)) = q;
        q.x = pkbf(tv2[0], tv2[1]);  q.y = pkbf(tv2[2], tv2[3]);
        q.z = pkbf(tv2[4], tv2[5]);  q.w = pkbf(tv2[6], tv2[7]);
        *(uint4*)((char*)t2s + ((base) ^ sw)) = q;
        q.x = pkbf(tv2[8], tv2[9]);  q.y = pkbf(tv2[10], tv2[11]);
        q.z = pkbf(tv2[12], tv2[13]); q.w = pkbf(tv2[14], tv2[15]);
        *(uint4*)((char*)t2s + ((base + 16) ^ sw)) = q;
    }
    __syncthreads();

    const int arow = wid * 16 + (lane & 15);
    const int asw  = (arow & 7) << 4;
    short8 a1[2], a2[2];
#pragma unroll
    for (int kt = 0; kt < 2; ++kt) {
        int ab = (arow * 128 + kt * 64 + ((lane >> 4) << 4)) ^ asw;
        a1[kt] = *(const short8*)((const char*)t1s + ab);
        a2[kt] = *(const short8*)((const char*)t2s + ab);
    }

    f32x4 acc1[4], acc2[4];
#pragma unroll
    for (int ct = 0; ct < 4; ++ct) {
        acc1[ct] = (f32x4){bb1[ct], bb1[ct], bb1[ct], bb1[ct]};
        acc2[ct] = (f32x4){bb2[ct], bb2[ct], bb2[ct], bb2[ct]};
    }
#pragma unroll
    for (int ct = 0; ct < 4; ++ct) {
        acc1[ct] = __builtin_amdgcn_mfma_f32_16x16x32_bf16(a1[0], w1f[0][ct], acc1[ct], 0, 0, 0);
        acc1[ct] = __builtin_amdgcn_mfma_f32_16x16x32_bf16(a1[1], w1f[1][ct], acc1[ct], 0, 0, 0);
        acc2[ct] = __builtin_amdgcn_mfma_f32_16x16x32_bf16(a2[0], w2f[0][ct], acc2[ct], 0, 0, 0);
        acc2[ct] = __builtin_amdgcn_mfma_f32_16x16x32_bf16(a2[1], w2f[1][ct], acc2[ct], 0, 0, 0);
    }

#pragma unroll
    for (int ct = 0; ct < 4; ++ct) {
        const int col = ct * 16 + (lane & 15);
#pragma unroll
        for (int r = 0; r < 4; ++r) {
            const int grow = node0 + wid * 16 + (lane >> 4) * 4 + r;
            if (grow < N_NODES) {
                float v1 = acc1[ct][r]; v1 = v1 > 0.f ? v1 : 0.01f * v1;
                float v2 = acc2[ct][r]; v2 = v2 > 0.f ? v2 : 0.01f * v2;
                float hnew = v1 + v2;
                h[(size_t)grow * DIM + col] = hnew;
                h_bf[(size_t)grow * DIM + col] = f2bf(hnew);
                out[(size_t)grow * OUT_COLS + out_col_base + col] = hnew;
            }
        }
    }
}

// ---------------------------------------------------------------------------
extern "C" void kernel_launch(void* const* d_in, const int* in_sizes, int n_in,
                              void* d_out, int out_size, void* d_ws, size_t ws_size,
                              hipStream_t stream) {
    const float* x   = (const float*)d_in[0];
    const float* a   = (const float*)d_in[1];
    const float* W1s = (const float*)d_in[2];
    const float* b1s = (const float*)d_in[3];
    const float* W2s = (const float*)d_in[4];
    const float* b2s = (const float*)d_in[5];
    const int*   src = (const int*)d_in[6];
    const int*   dst = (const int*)d_in[7];
    float* out = (float*)d_out;

    // workspace layout
    float* h  = (float*)d_ws;                              // [N, 64] fp32
    float* hn = h + (size_t)N_NODES * DIM;                 // [N, 64] fp32 (doubles as binA staging)
    unsigned short* h_bf = (unsigned short*)(hn + (size_t)N_NODES * DIM); // [N,64] bf16
    int* offsets       = (int*)(h_bf + (size_t)N_NODES * DIM);  // [N+1]
    int* bucket_count  = offsets + N_NODES + 1;            // [NBUCK]
    int* bucket_base   = bucket_count + NBUCK;             // [NBUCK]
    uintptr_t p = (uintptr_t)(bucket_base + NBUCK);
    p = (p + 15) & ~(uintptr_t)15;
    int2* edges = (int2*)p;                                // [E]
    int2* temp  = (int2*)hn;                               // binA staging
    uintptr_t p2 = (uintptr_t)(edges + N_EDGES);
    p2 = (p2 + 15) & ~(uintptr_t)15;
    unsigned short* wfrag = (unsigned short*)p2;           // [3 * 8192] bf16 frags
    uintptr_t p3 = (uintptr_t)(wfrag + 3 * WFRAG_PER_LAYER);
    p3 = (p3 + 15) & ~(uintptr_t)15;
    int* mat = (int*)p3;                                   // [NTILEBLK * NBUCK]

    // h = x ; h_bf = bf16(x) ; out[:, :64] = x
    {
        int total = N_NODES * DIM / 4;
        init_kernel<<<(total + 255) / 256, 256, 0, stream>>>(x, h, h_bf, out);
    }

    // pack weight fragments
    wprep_kernel<<<(3 * WFRAG_PER_LAYER + 255) / 256, 256, 0, stream>>>(W1s, W2s, wfrag);

    // CSR build — zero global atomics
    count_kernel<<<NTILEBLK, 256, 0, stream>>>(dst, mat);
    scan2_kernel<<<NBUCK, 256, 0, stream>>>(mat, bucket_count);
    bucket_scan_kernel<<<1, 512, 0, stream>>>(bucket_count, bucket_base, offsets);
    binA_kernel<<<NTILEBLK, 256, 0, stream>>>(src, dst, a, bucket_base, mat, temp);
    binB_kernel<<<NBUCK, 256, 0, stream>>>(temp, bucket_base, bucket_count, offsets, edges);

    for (int l = 0; l < 3; ++l) {
        int waves = (N_NODES + 1) / 2;
        int blocks = (waves * 64 + 255) / 256;
        gather_kernel<<<blocks, 256, 0, stream>>>(h_bf, edges, offsets, hn);
        update_kernel<<<NODE_TILES, 256, 0, stream>>>(
            h, h_bf, hn,
            wfrag + (size_t)l * WFRAG_PER_LAYER,
            b1s + (size_t)l * DIM,
            b2s + (size_t)l * DIM,
            out, (l + 1) * DIM);
    }
}